// Round 5
// baseline (299.257 us; speedup 1.0000x reference)
//
#include <hip/hip_runtime.h>

// GenerateNodes: out[n,t,o,k] = sum_c mix[n,t,c] * W[k,o,c] + b[k,o]
// mix = concat(x [16384,3200], seeds [16384,15])  -> GEMM M=16384, K=3215, Ncol=60
// Round 5: remove the per-chunk vmcnt(0) barrier drain (T3+T4 counted-vmcnt).
// 8-slot LDS ring (64 KiB), 1 kb-block per slot, depth-6 prefetch via
// global_load_lds; each wave issues exactly 2 loads per stage, so
// "s_waitcnt vmcnt(12); s_barrier" guarantees chunk c landed while keeping
// 6 chunks (48 KB/block) permanently in flight. Slot-reuse is race-free:
// stage(c+6) issues after barrier(c-1), which follows compute(c-2), the
// previous reader of slot (c+6)&7. Tail steps the immediate 12->...->0.
// 512 blocks x 32 rows, 4 waves = 2 row-tiles x 2 col-halves.

#define NROWS    16384
#define CIN      3200
#define SEED_K   15
#define LIN_IN   3215
#define NCOL     60
#define KB_MAIN  100          // 3200 / 32
#define WB_ELEMS ((KB_MAIN + 1) * 4 * 64 * 8)
#define NCHUNKS  100          // one kb-block per pipeline chunk
#define DEPTH    6            // chunks prefetched ahead
#define SLOT_SZ  4096         // per-chunk A (or B) bytes: 4 slices x 64 lanes x 16 B
#define B_BASE   32768        // B region offset in smem
#define SMEM_SZ  65536        // 8 slots x 4 KB (A) + 8 slots x 4 KB (B)

typedef __attribute__((ext_vector_type(8))) __bf16 bf16x8;
typedef __attribute__((ext_vector_type(4))) float f32x4;
typedef __attribute__((ext_vector_type(8))) unsigned short ushort8;

__device__ unsigned short Wb_g[WB_ELEMS];
__device__ __align__(16) float bias_g[64];

__device__ inline unsigned short f2bf_rne(float f) {
    unsigned int u = __builtin_bit_cast(unsigned int, f);
    u += 0x7fffu + ((u >> 16) & 1u);
    return (unsigned short)(u >> 16);
}

__device__ inline bf16x8 to_bf16x8(f32x4 a0, f32x4 a1) {
    ushort8 u;
    u[0] = f2bf_rne(a0[0]); u[1] = f2bf_rne(a0[1]);
    u[2] = f2bf_rne(a0[2]); u[3] = f2bf_rne(a0[3]);
    u[4] = f2bf_rne(a1[0]); u[5] = f2bf_rne(a1[1]);
    u[6] = f2bf_rne(a1[2]); u[7] = f2bf_rne(a1[3]);
    return __builtin_bit_cast(bf16x8, u);
}

// global -> LDS direct (16 B per lane; dest = uniform base + lane*16).
typedef __attribute__((address_space(3))) void lds_void;
typedef __attribute__((address_space(1))) const void gm_void;
__device__ __forceinline__ void gll16(const void* g, void* l) {
    __builtin_amdgcn_global_load_lds((gm_void*)g, (lds_void*)l, 16, 0, 0);
}

// counted-vmcnt barrier: no reordering across (memory clobber), never
// drains the load queue to 0 in the main loop.
#define VB(N) asm volatile("s_waitcnt vmcnt(" #N ")\n\ts_barrier" ::: "memory")

// Pack W[20,3,3215] fp32 into bf16 B-fragment order:
// Wb[kb][nt][lane][jj] = B[k = kb*32 + (lane>>4)*8 + jj][n = nt*16 + (lane&15)]
// where B[c][j] = W[j%20][j/20][c]; zero-pad k>=3215 and n>=60.
// Also stages the transposed bias vector bias_g[j] = b[j%20][j/20].
__global__ void prep_B(const float* __restrict__ W, const float* __restrict__ b) {
    int idx = blockIdx.x * blockDim.x + threadIdx.x;
    if (idx >= WB_ELEMS) return;
    if (idx < 64) bias_g[idx] = (idx < NCOL) ? b[(idx % 20) * 3 + (idx / 20)] : 0.f;
    int jj   = idx & 7;
    int lane = (idx >> 3) & 63;
    int nt   = (idx >> 9) & 3;
    int kb   = idx >> 11;
    int k = kb * 32 + (lane >> 4) * 8 + jj;
    int n = nt * 16 + (lane & 15);
    float v = 0.0f;
    if (k < LIN_IN && n < NCOL) {
        int o = n / 20, kn = n % 20;
        v = W[(kn * 3 + o) * LIN_IN + k];
    }
    Wb_g[idx] = f2bf_rne(v);
}

__global__ __launch_bounds__(256) void gen_nodes(
    const float* __restrict__ x, const float* __restrict__ seeds,
    float* __restrict__ out) {
    const int lane = threadIdx.x & 63;
    const int wave = threadIdx.x >> 6;
    const int quad = lane >> 4;
    const int l15  = lane & 15;
    const int rb0  = blockIdx.x * 32;       // 32 rows per block
    const int wt   = wave & 1;              // row-tile (16 rows) for compute
    const int nh   = wave >> 1;             // col-half (nt pair) for compute

    __shared__ __align__(16) char smem[SMEM_SZ];

    // Stage sources: wave w stages A slice w (row-tile w>>1, half w&1) and
    // B slice w (nt = w) of each kb chunk.  2 global_load_lds per stage.
    const float* aSrc = x + (size_t)(rb0 + (wave >> 1) * 16 + l15) * CIN
                          + quad * 8 + (wave & 1) * 4;
    const unsigned short* bSrc = Wb_g + wave * 512 + lane * 8;

    f32x4 acc[2];
    acc[0] = (f32x4){0.f, 0.f, 0.f, 0.f};
    acc[1] = (f32x4){0.f, 0.f, 0.f, 0.f};

    auto stage = [&](int cbk) {
        int slot = cbk & 7;
        gll16(aSrc + (size_t)cbk * 32, smem + slot * SLOT_SZ + wave * 1024);
        gll16(bSrc + (size_t)cbk * 2048,
              smem + B_BASE + slot * SLOT_SZ + wave * 1024);
    };

#pragma unroll
    for (int c0 = 0; c0 < DEPTH; ++c0) stage(c0);

    for (int c = 0; c < NCHUNKS; ++c) {
        if (c + DEPTH < NCHUNKS) {
            stage(c + DEPTH);
            VB(12);
        } else {
            int ah = NCHUNKS - 1 - c;          // chunks still in flight past c
            if      (ah >= 5) VB(10);
            else if (ah == 4) VB(8);
            else if (ah == 3) VB(6);
            else if (ah == 2) VB(4);
            else if (ah == 1) VB(2);
            else              VB(0);
        }

        const int slot = c & 7;
        const char* ab = smem + slot * SLOT_SZ + wt * 2048 + lane * 16;
        f32x4 a0 = *(const f32x4*)(ab);
        f32x4 a1 = *(const f32x4*)(ab + 1024);
        const char* bb = smem + B_BASE + slot * SLOT_SZ + nh * 2048 + lane * 16;
        bf16x8 b0 = *(const bf16x8*)(bb);
        bf16x8 b1 = *(const bf16x8*)(bb + 1024);
        bf16x8 af = to_bf16x8(a0, a1);
        acc[0] = __builtin_amdgcn_mfma_f32_16x16x32_bf16(af, b0, acc[0], 0, 0, 0);
        acc[1] = __builtin_amdgcn_mfma_f32_16x16x32_bf16(af, b1, acc[1], 0, 0, 0);
    }

    // Seed tail (k = 3200..3214), kb index 100, B from global (L2-hot).
    {
        const float* srow = seeds + (size_t)(rb0 + wt * 16 + l15) * SEED_K;
        f32x4 s0 = {0.f, 0.f, 0.f, 0.f}, s1 = {0.f, 0.f, 0.f, 0.f};
#pragma unroll
        for (int j = 0; j < 4; ++j) {
            int cc = quad * 8 + j;
            if (cc < SEED_K) s0[j] = srow[cc];
            if (cc + 4 < SEED_K) s1[j] = srow[cc + 4];
        }
        bf16x8 af = to_bf16x8(s0, s1);
        const unsigned short* bb = Wb_g + (size_t)KB_MAIN * 2048 + lane * 8;
        bf16x8 b0 = *(const bf16x8*)(bb + nh * 1024);
        bf16x8 b1 = *(const bf16x8*)(bb + nh * 1024 + 512);
        acc[0] = __builtin_amdgcn_mfma_f32_16x16x32_bf16(af, b0, acc[0], 0, 0, 0);
        acc[1] = __builtin_amdgcn_mfma_f32_16x16x32_bf16(af, b1, acc[1], 0, 0, 0);
    }

    // Epilogue: C/D layout col = lane&15, row = quad*4 + reg. j = nt*16 + col.
#pragma unroll
    for (int t = 0; t < 2; ++t) {
        int j = (nh * 2 + t) * 16 + l15;
        if (j < NCOL) {
            float bias = bias_g[j];
#pragma unroll
            for (int r = 0; r < 4; ++r) {
                int m = wt * 16 + quad * 4 + r;
                out[(size_t)(rb0 + m) * NCOL + j] = acc[t][r] + bias;
            }
        }
    }
}

extern "C" void kernel_launch(void* const* d_in, const int* in_sizes, int n_in,
                              void* d_out, int out_size, void* d_ws, size_t ws_size,
                              hipStream_t stream) {
    const float* x     = (const float*)d_in[0];
    const float* seeds = (const float*)d_in[1];
    const float* W     = (const float*)d_in[2];
    const float* b     = (const float*)d_in[3];
    float* out = (float*)d_out;
    (void)d_ws; (void)ws_size;

    prep_B<<<(WB_ELEMS + 255) / 256, 256, 0, stream>>>(W, b);
    gen_nodes<<<NROWS / 32, 256, 0, stream>>>(x, seeds, out);
}

// Round 6
// 289.713 us; speedup vs baseline: 1.0329x; 1.0329x over previous
//
#include <hip/hip_runtime.h>

// GenerateNodes: out[n,t,o,k] = sum_c mix[n,t,c] * W[k,o,c] + b[k,o]
// mix = concat(x [16384,3200], seeds [16384,15])  -> GEMM M=16384, K=3215, Ncol=60
// Round 6: minimize vmem transactions. A staging now reads 4 rows x 256 B
// contiguous per global_load_lds (16 fully-used 64B segments/inst, the
// data-inherent minimum) instead of 16 rows x 16B pieces at 32B stride
// (32 half-used segments). LDS dest stays linear (required); the resulting
// row-major [32][256B] A tile would 16-way bank-conflict on fragment reads,
// so the piece index is XOR-swizzled with (row&7) on the GLOBAL source and
// the same XOR is applied to the ds_read address (both-sides swizzle).
// 2-kb chunk pairs, 4-slot ring (64 KiB LDS, 2 blocks/CU), depth-2 counted
// vmcnt(8). 512 blocks x 32 rows, 4 waves = 2 row-tiles x 2 col-halves.

#define NROWS    16384
#define CIN      3200
#define SEED_K   15
#define LIN_IN   3215
#define NCOL     60
#define KB_MAIN  100          // 3200 / 32
#define WB_ELEMS ((KB_MAIN + 1) * 4 * 64 * 8)
#define NPAIRS   50           // two kb-blocks per pipeline chunk
#define SLOT_SZ  8192         // per-pair A (or B) bytes
#define B_BASE   32768        // B region offset in smem
#define SMEM_SZ  65536        // 4 slots x 8 KB (A) + 4 slots x 8 KB (B)

typedef __attribute__((ext_vector_type(8))) __bf16 bf16x8;
typedef __attribute__((ext_vector_type(4))) float f32x4;
typedef __attribute__((ext_vector_type(8))) unsigned short ushort8;

__device__ unsigned short Wb_g[WB_ELEMS];
__device__ __align__(16) float bias_g[64];

__device__ inline unsigned short f2bf_rne(float f) {
    unsigned int u = __builtin_bit_cast(unsigned int, f);
    u += 0x7fffu + ((u >> 16) & 1u);
    return (unsigned short)(u >> 16);
}

__device__ inline bf16x8 to_bf16x8(f32x4 a0, f32x4 a1) {
    ushort8 u;
    u[0] = f2bf_rne(a0[0]); u[1] = f2bf_rne(a0[1]);
    u[2] = f2bf_rne(a0[2]); u[3] = f2bf_rne(a0[3]);
    u[4] = f2bf_rne(a1[0]); u[5] = f2bf_rne(a1[1]);
    u[6] = f2bf_rne(a1[2]); u[7] = f2bf_rne(a1[3]);
    return __builtin_bit_cast(bf16x8, u);
}

// global -> LDS direct (16 B per lane; dest = uniform base + lane*16).
typedef __attribute__((address_space(3))) void lds_void;
typedef __attribute__((address_space(1))) const void gm_void;
__device__ __forceinline__ void gll16(const void* g, void* l) {
    __builtin_amdgcn_global_load_lds((gm_void*)g, (lds_void*)l, 16, 0, 0);
}

// counted-vmcnt barrier: never drains the load queue to 0 in the main loop.
#define VB(N) asm volatile("s_waitcnt vmcnt(" #N ")\n\ts_barrier" ::: "memory")

// Pack W[20,3,3215] fp32 into bf16 B-fragment order:
// Wb[kb][nt][lane][jj] = B[k = kb*32 + (lane>>4)*8 + jj][n = nt*16 + (lane&15)]
// where B[c][j] = W[j%20][j/20][c]; zero-pad k>=3215 and n>=60.
// Also stages the transposed bias vector bias_g[j] = b[j%20][j/20].
__global__ void prep_B(const float* __restrict__ W, const float* __restrict__ b) {
    int idx = blockIdx.x * blockDim.x + threadIdx.x;
    if (idx >= WB_ELEMS) return;
    if (idx < 64) bias_g[idx] = (idx < NCOL) ? b[(idx % 20) * 3 + (idx / 20)] : 0.f;
    int jj   = idx & 7;
    int lane = (idx >> 3) & 63;
    int nt   = (idx >> 9) & 3;
    int kb   = idx >> 11;
    int k = kb * 32 + (lane >> 4) * 8 + jj;
    int n = nt * 16 + (lane & 15);
    float v = 0.0f;
    if (k < LIN_IN && n < NCOL) {
        int o = n / 20, kn = n % 20;
        v = W[(kn * 3 + o) * LIN_IN + k];
    }
    Wb_g[idx] = f2bf_rne(v);
}

__global__ __launch_bounds__(256) void gen_nodes(
    const float* __restrict__ x, const float* __restrict__ seeds,
    float* __restrict__ out) {
    const int lane = threadIdx.x & 63;
    const int wave = threadIdx.x >> 6;
    const int quad = lane >> 4;
    const int l15  = lane & 15;
    const int rb0  = blockIdx.x * 32;       // 32 rows per block
    const int wt   = wave & 1;              // row-tile (16 rows) for compute
    const int nh   = wave >> 1;             // col-half (nt pair) for compute

    __shared__ __align__(16) char smem[SMEM_SZ];

    // ---- A stage mapping (inst (wave, h), this lane) ----------------------
    // row m = h*16 + wave*4 + (lane>>4); swizzle s = m&7 = (wave*4+(lane>>4))&7;
    // piece p = (lane&15) ^ s;  global = x[(rb0+m)*CIN + cp*64 + p*4 ..+3]
    // LDS dest = slot + h*4096 + wave*1024 + lane*16  (= slot + m*256 + (lane&15)*16)
    const int r4 = lane >> 4;
    const int sw = (wave * 4 + r4) & 7;
    const int pp = (lane & 15) ^ sw;
    const float* aS0 = x + (size_t)(rb0 + wave * 4 + r4) * CIN + pp * 4;
    const float* aS1 = aS0 + (size_t)16 * CIN;
    const unsigned short* bS = Wb_g + wave * 512 + lane * 8;

    f32x4 acc[2];
    acc[0] = (f32x4){0.f, 0.f, 0.f, 0.f};
    acc[1] = (f32x4){0.f, 0.f, 0.f, 0.f};

    auto stage = [&](int cp) {
        const int slot = cp & 3;
        char* ad = smem + slot * SLOT_SZ + wave * 1024 + lane * 16;
        gll16(aS0 + (size_t)cp * 64, ad);
        gll16(aS1 + (size_t)cp * 64, ad + 4096);
        char* bd = smem + B_BASE + slot * SLOT_SZ + wave * 1024 + lane * 16;
        gll16(bS + (size_t)(2 * cp) * 2048, bd);
        gll16(bS + (size_t)(2 * cp + 1) * 2048, bd + 4096);
    };

    stage(0);
    stage(1);

    const int mrow = wt * 16 + l15;               // compute row
    const int srd  = l15 & 7;                     // read-side swizzle (= mrow&7)
    const char* arow_lds = smem + mrow * 256;
    const char* bcol_lds = smem + B_BASE + nh * 2048 + lane * 16;

    for (int cp = 0; cp < NPAIRS; ++cp) {
        if (cp + 2 < NPAIRS) {
            stage(cp + 2);
            VB(8);
        } else if (cp + 2 == NPAIRS) {
            VB(4);
        } else {
            VB(0);
        }

        const int sb = (cp & 3) * SLOT_SZ;
#pragma unroll
        for (int i = 0; i < 2; ++i) {
            const int p0 = quad * 2 + i * 8;
            f32x4 a0 = *(const f32x4*)(arow_lds + sb + ((p0)     ^ srd) * 16);
            f32x4 a1 = *(const f32x4*)(arow_lds + sb + ((p0 + 1) ^ srd) * 16);
            const char* bb = bcol_lds + sb + i * 4096;
            bf16x8 b0 = *(const bf16x8*)(bb);
            bf16x8 b1 = *(const bf16x8*)(bb + 1024);
            bf16x8 af = to_bf16x8(a0, a1);
            acc[0] = __builtin_amdgcn_mfma_f32_16x16x32_bf16(af, b0, acc[0], 0, 0, 0);
            acc[1] = __builtin_amdgcn_mfma_f32_16x16x32_bf16(af, b1, acc[1], 0, 0, 0);
        }
    }

    // Seed tail (k = 3200..3214), kb index 100, B from global (L2-hot).
    {
        const float* srow = seeds + (size_t)(rb0 + mrow) * SEED_K;
        f32x4 s0 = {0.f, 0.f, 0.f, 0.f}, s1 = {0.f, 0.f, 0.f, 0.f};
#pragma unroll
        for (int j = 0; j < 4; ++j) {
            int cc = quad * 8 + j;
            if (cc < SEED_K) s0[j] = srow[cc];
            if (cc + 4 < SEED_K) s1[j] = srow[cc + 4];
        }
        bf16x8 af = to_bf16x8(s0, s1);
        const unsigned short* bb = Wb_g + (size_t)KB_MAIN * 2048 + lane * 8;
        bf16x8 b0 = *(const bf16x8*)(bb + nh * 1024);
        bf16x8 b1 = *(const bf16x8*)(bb + nh * 1024 + 512);
        acc[0] = __builtin_amdgcn_mfma_f32_16x16x32_bf16(af, b0, acc[0], 0, 0, 0);
        acc[1] = __builtin_amdgcn_mfma_f32_16x16x32_bf16(af, b1, acc[1], 0, 0, 0);
    }

    // Epilogue: C/D layout col = lane&15, row = quad*4 + reg. j = nt*16 + col.
#pragma unroll
    for (int t = 0; t < 2; ++t) {
        int j = (nh * 2 + t) * 16 + l15;
        if (j < NCOL) {
            float bias = bias_g[j];
#pragma unroll
            for (int r = 0; r < 4; ++r) {
                int m = wt * 16 + quad * 4 + r;
                out[(size_t)(rb0 + m) * NCOL + j] = acc[t][r] + bias;
            }
        }
    }
}

extern "C" void kernel_launch(void* const* d_in, const int* in_sizes, int n_in,
                              void* d_out, int out_size, void* d_ws, size_t ws_size,
                              hipStream_t stream) {
    const float* x     = (const float*)d_in[0];
    const float* seeds = (const float*)d_in[1];
    const float* W     = (const float*)d_in[2];
    const float* b     = (const float*)d_in[3];
    float* out = (float*)d_out;
    (void)d_ws; (void)ws_size;

    prep_B<<<(WB_ELEMS + 255) / 256, 256, 0, stream>>>(W, b);
    gen_nodes<<<NROWS / 32, 256, 0, stream>>>(x, seeds, out);
}